// Round 4
// baseline (1386.393 us; speedup 1.0000x reference)
//
#include <hip/hip_runtime.h>

typedef __attribute__((ext_vector_type(8))) short bf16x8;
typedef __attribute__((ext_vector_type(4))) float f32x4;

#define MFMA16(a, b, c) __builtin_amdgcn_mfma_f32_16x16x32_bf16(a, b, c, 0, 0, 0)

__device__ __forceinline__ unsigned short f2bf(float f) {
    unsigned int u = __float_as_uint(f);
    u += 0x7FFFu + ((u >> 16) & 1u);
    return (unsigned short)(u >> 16);
}
__device__ __forceinline__ float bf2f(unsigned short h) {
    return __uint_as_float(((unsigned int)h) << 16);
}

// ---------------- weight conversion: 6 tensors x [2,256,256] f32 -> bf16 ----
struct WPtrs { const float* p[6]; };

__global__ __launch_bounds__(256) void conv_w_kernel(WPtrs wp, unsigned short* dst) {
    int idx = blockIdx.x * 256 + threadIdx.x;
    if (idx >= 196608) return;
    int t = idx >> 15;
    int q = idx & 32767;
    float4 v = *(const float4*)(wp.p[t] + ((size_t)q << 2));
    ushort4 o;
    o.x = f2bf(v.x); o.y = f2bf(v.y); o.z = f2bf(v.z); o.w = f2bf(v.w);
    *(ushort4*)(dst + ((size_t)t << 17) + ((size_t)q << 2)) = o;
}

// ---- t_in: feats f32 [b][c][r][q] -> bf16 seq-major [b][r][q][c] -----------
__global__ __launch_bounds__(256) void t_in(const float* __restrict__ feats,
                                            unsigned short* __restrict__ dst) {
    __shared__ unsigned short t[96 * 257];          // [q][c], stride 257
    const int b = blockIdx.x / 96, r = blockIdx.x % 96;
    const int tid = threadIdx.x;
    for (int i = tid; i < 6144; i += 256) {         // c-major read (q-contig rows)
        const int c = i / 24, q4 = i % 24;
        float4 v = *(const float4*)(feats + ((size_t)(b * 256 + c) * 9216) + r * 96 + q4 * 4);
        t[(q4 * 4 + 0) * 257 + c] = f2bf(v.x);
        t[(q4 * 4 + 1) * 257 + c] = f2bf(v.y);
        t[(q4 * 4 + 2) * 257 + c] = f2bf(v.z);
        t[(q4 * 4 + 3) * 257 + c] = f2bf(v.w);
    }
    __syncthreads();
    for (int i = tid; i < 3072; i += 256) {         // q-major write (c-contig rows)
        const int q = i / 32, co = i % 32;
        unsigned short ob[8];
#pragma unroll
        for (int j = 0; j < 8; ++j) ob[j] = t[q * 257 + co * 8 + j];
        *(uint4*)(dst + ((size_t)(b * 96 + r) * 96 + q) * 256 + co * 8) = *(const uint4*)ob;
    }
}

// ---- final_k: bf16 [b][r][q][c] -> f32 [b][c][r][q] ------------------------
__global__ __launch_bounds__(256) void final_k(const unsigned short* __restrict__ x,
                                               float* __restrict__ out) {
    __shared__ unsigned short t[256 * 97];          // [c][q], stride 97
    const int b = blockIdx.x / 96, r = blockIdx.x % 96;
    const int tid = threadIdx.x;
    const unsigned short* sg = x + (size_t)(b * 96 + r) * 24576;
    for (int i = tid; i < 3072; i += 256) {         // read c-contig rows
        const int q = i / 32, co = i % 32;
        uint4 v = *(const uint4*)(sg + (size_t)q * 256 + co * 8);
        const unsigned short* pv = (const unsigned short*)&v;
#pragma unroll
        for (int j = 0; j < 8; ++j) t[(co * 8 + j) * 97 + q] = pv[j];
    }
    __syncthreads();
    for (int i = tid; i < 6144; i += 256) {         // write q-contig rows
        const int c = i / 24, q4 = i % 24;
        float4 f;
        f.x = bf2f(t[c * 97 + q4 * 4 + 0]);
        f.y = bf2f(t[c * 97 + q4 * 4 + 1]);
        f.z = bf2f(t[c * 97 + q4 * 4 + 2]);
        f.w = bf2f(t[c * 97 + q4 * 4 + 3]);
        *(float4*)(out + ((size_t)(b * 256 + c) * 9216) + r * 96 + q4 * 4) = f;
    }
}

// ---------------- masks output ----------------------------------------------
__global__ __launch_bounds__(256) void masks_kernel(const int* __restrict__ nr,
                                                    const int* __restrict__ nc,
                                                    float* __restrict__ out) {
    int i = blockIdx.x * 256 + threadIdx.x;
    if (i >= 147456) return;
    int b = i / 9216, rem = i % 9216, r = rem / 96, c = rem % 96;
    out[i] = (r < nr[b] && c < nc[b]) ? 1.0f : 0.0f;
}

// ---------------- per-(sequence, head) fused self-attention -----------------
// x seq-major: [b][s][n][c] (s = sequence, n = position, c = channel).
// Block (b,s,h): reads x[b][s][:][:] direct from global (L1/L2-hot),
// writes out[b][n][s][h*64..] -> next stage's layout (fused transpose).
// LDS (40960 B): Kt[96][72]@0, Qt[96][72]@13824, Vm[64][104]@27648;
// Pm[96][104]@0 overlays Kt+Qt after QK; OT[64][101]f32@0 overlays Pm after PV.
#define KT_S 72
#define VM_S 104
#define PM_S 104
#define OT_S 101

__global__ __launch_bounds__(384, 4) void sa3(
    const unsigned short* __restrict__ src, unsigned short* __restrict__ dst,
    const unsigned short* __restrict__ Wk, const unsigned short* __restrict__ Wq,
    const unsigned short* __restrict__ Wv,
    const float* __restrict__ bk, const float* __restrict__ bq, const float* __restrict__ bv,
    const int* __restrict__ lim_s, const int* __restrict__ lim_m) {
    extern __shared__ char smem[];
    unsigned short* Kt = (unsigned short*)smem;
    unsigned short* Qt = (unsigned short*)(smem + 13824);
    unsigned short* Vm = (unsigned short*)(smem + 27648);
    unsigned short* Pm = (unsigned short*)smem;     // after QK
    float*          OT = (float*)smem;              // after PV

    // bid swizzle: 4 h-siblings of a seq land on bids == so8 (mod 8) -> same XCD
    const int bid = blockIdx.x;
    const int grp = bid >> 5, l5 = bid & 31;
    const int h = l5 >> 3;
    const int seq = grp * 8 + (l5 & 7);
    const int b = seq / 96, s = seq % 96;
    const int tid = threadIdx.x;

    const unsigned short* sg = src + (size_t)seq * 24576;

    if (s >= lim_s[b]) {                            // masked seq: out = x (relayout copy)
        for (int i = tid; i < 768; i += 384) {
            const int n = i >> 3, c8 = i & 7;
            uint4 v = *(const uint4*)(sg + (size_t)n * 256 + h * 64 + c8 * 8);
            *(uint4*)(dst + ((size_t)(b * 96 + n) * 96 + s) * 256 + h * 64 + c8 * 8) = v;
        }
        return;
    }
    const int mlim = lim_m[b];

    const int wave = tid >> 6, lane = tid & 63, lr = lane & 15, lk = lane >> 4;
    const int p = wave >> 1, g = wave & 1;
    const unsigned short* Wp = (p == 0) ? Wk : (p == 1) ? Wq : Wv;
    const float* bp = (p == 0) ? bk : (p == 1) ? bq : bv;

    // ---- projection: A,B fragments direct from global (no LDS staging) ----
    f32x4 acc[2][6];
#pragma unroll
    for (int dt = 0; dt < 2; ++dt)
#pragma unroll
        for (int nt = 0; nt < 6; ++nt) acc[dt][nt] = (f32x4)0.0f;

    const unsigned short* xb = sg + lr * 256 + lk * 8;
    const unsigned short* wb = Wp + (size_t)(h * 64 + g * 32 + lr) * 256 + lk * 8;
#pragma unroll
    for (int cc = 0; cc < 8; ++cc) {
        bf16x8 bfr[6];
#pragma unroll
        for (int nt = 0; nt < 6; ++nt)
            bfr[nt] = *(const bf16x8*)(xb + nt * 4096 + cc * 32);
#pragma unroll
        for (int dt = 0; dt < 2; ++dt) {
            bf16x8 afr = *(const bf16x8*)(wb + dt * 4096 + cc * 32);
#pragma unroll
            for (int nt = 0; nt < 6; ++nt)
                acc[dt][nt] = MFMA16(afr, bfr[nt], acc[dt][nt]);
        }
    }

    __syncthreads();   // (1) prior head's epilogue done with OT region

    // ---- bias + store K/Q/V to LDS ----------------------------------------
#pragma unroll
    for (int dt = 0; dt < 2; ++dt) {
        const int dbase = g * 32 + dt * 16 + lk * 4;
        const float b0 = bp[h * 64 + dbase + 0], b1 = bp[h * 64 + dbase + 1];
        const float b2 = bp[h * 64 + dbase + 2], b3 = bp[h * 64 + dbase + 3];
#pragma unroll
        for (int nt = 0; nt < 6; ++nt) {
            const int n = nt * 16 + lr;
            if (p == 2) {
                Vm[(dbase + 0) * VM_S + n] = f2bf(acc[dt][nt][0] + b0);
                Vm[(dbase + 1) * VM_S + n] = f2bf(acc[dt][nt][1] + b1);
                Vm[(dbase + 2) * VM_S + n] = f2bf(acc[dt][nt][2] + b2);
                Vm[(dbase + 3) * VM_S + n] = f2bf(acc[dt][nt][3] + b3);
            } else {
                ushort4 o;
                o.x = f2bf(acc[dt][nt][0] + b0);
                o.y = f2bf(acc[dt][nt][1] + b1);
                o.z = f2bf(acc[dt][nt][2] + b2);
                o.w = f2bf(acc[dt][nt][3] + b3);
                *(ushort4*)&((p == 0 ? Kt : Qt)[n * KT_S + dbase]) = o;
            }
        }
    }
    __syncthreads();   // (2)

    // ---- QK^T: wave = n-tile, all m in registers --------------------------
    f32x4 acc2[6];
#pragma unroll
    for (int mt = 0; mt < 6; ++mt) acc2[mt] = (f32x4)0.0f;
#pragma unroll
    for (int k0 = 0; k0 < 64; k0 += 32) {
        bf16x8 kf = *(const bf16x8*)&Kt[(wave * 16 + lr) * KT_S + k0 + lk * 8];
#pragma unroll
        for (int mt = 0; mt < 6; ++mt) {
            bf16x8 qf = *(const bf16x8*)&Qt[(mt * 16 + lr) * KT_S + k0 + lk * 8];
            acc2[mt] = MFMA16(kf, qf, acc2[mt]);
        }
    }
    __syncthreads();   // (3) Kt/Qt dead; Pm may overlay

    // ---- in-register masked softmax over m --------------------------------
    float lg[6][4];
#pragma unroll
    for (int mt = 0; mt < 6; ++mt) {
        const bool valid = (mt * 16 + lr) < mlim;
#pragma unroll
        for (int r2 = 0; r2 < 4; ++r2)
            lg[mt][r2] = valid ? acc2[mt][r2] * 0.125f : -3.0e38f;
    }
#pragma unroll
    for (int r2 = 0; r2 < 4; ++r2) {
        float mx = lg[0][r2];
#pragma unroll
        for (int mt = 1; mt < 6; ++mt) mx = fmaxf(mx, lg[mt][r2]);
        mx = fmaxf(mx, __shfl_xor(mx, 1));
        mx = fmaxf(mx, __shfl_xor(mx, 2));
        mx = fmaxf(mx, __shfl_xor(mx, 4));
        mx = fmaxf(mx, __shfl_xor(mx, 8));
        float sm = 0.0f;
#pragma unroll
        for (int mt = 0; mt < 6; ++mt) {
            float e = __expf(lg[mt][r2] - mx);
            lg[mt][r2] = e;
            sm += e;
        }
        sm += __shfl_xor(sm, 1);
        sm += __shfl_xor(sm, 2);
        sm += __shfl_xor(sm, 4);
        sm += __shfl_xor(sm, 8);
        const float inv = 1.0f / sm;
        const int n = wave * 16 + lk * 4 + r2;
#pragma unroll
        for (int mt = 0; mt < 6; ++mt)
            Pm[n * PM_S + mt * 16 + lr] = f2bf(lg[mt][r2] * inv);
    }
    __syncthreads();   // (4)

    // ---- PV: wave = n-tile ------------------------------------------------
    f32x4 acc3[4];
#pragma unroll
    for (int dt = 0; dt < 4; ++dt) acc3[dt] = (f32x4)0.0f;
    const int nk = (mlim + 31) >> 5;
    for (int k0i = 0; k0i < nk; ++k0i) {
        const int k0 = k0i * 32;
        bf16x8 pf = *(const bf16x8*)&Pm[(wave * 16 + lr) * PM_S + k0 + lk * 8];
#pragma unroll
        for (int dt = 0; dt < 4; ++dt) {
            bf16x8 vf = *(const bf16x8*)&Vm[(dt * 16 + lr) * VM_S + k0 + lk * 8];
            acc3[dt] = MFMA16(vf, pf, acc3[dt]);
        }
    }
    __syncthreads();   // (5) Pm/Vm reads done; OT may overlay

#pragma unroll
    for (int dt = 0; dt < 4; ++dt)
#pragma unroll
        for (int r2 = 0; r2 < 4; ++r2)
            OT[(dt * 16 + lk * 4 + r2) * OT_S + wave * 16 + lr] = acc3[dt][r2];
    __syncthreads();   // (6)

    // ---- epilogue: residual + fused-transpose store -----------------------
    for (int i = tid; i < 768; i += 384) {
        const int n = i >> 3, c8 = i & 7;
        uint4 rv = *(const uint4*)(sg + (size_t)n * 256 + h * 64 + c8 * 8);
        const unsigned short* rs = (const unsigned short*)&rv;
        unsigned short ob[8];
#pragma unroll
        for (int j = 0; j < 8; ++j)
            ob[j] = f2bf(OT[(c8 * 8 + j) * OT_S + n] + bf2f(rs[j]));
        *(uint4*)(dst + ((size_t)(b * 96 + n) * 96 + s) * 256 + h * 64 + c8 * 8) = *(const uint4*)ob;
    }
}

// ---------------------------------------------------------------------------
extern "C" void kernel_launch(void* const* d_in, const int* in_sizes, int n_in,
                              void* d_out, int out_size, void* d_ws, size_t ws_size,
                              hipStream_t stream) {
    const float* feats    = (const float*)d_in[0];
    const int*   num_rows = (const int*)d_in[1];
    const int*   num_cols = (const int*)d_in[2];

    unsigned short* bufA = (unsigned short*)d_ws;                       // 75497472 B
    unsigned short* wbuf = (unsigned short*)((char*)d_ws + 75497472);   // 1572864 B
    unsigned short* bufB = (unsigned short*)d_out;                      // scratch until final_k

    WPtrs wp;
    for (int t = 0; t < 6; ++t) wp.p[t] = (const float*)d_in[3 + 2 * t];

    (void)hipFuncSetAttribute((const void*)sa3,
                              hipFuncAttributeMaxDynamicSharedMemorySize, 40960);

    conv_w_kernel<<<768, 256, 0, stream>>>(wp, wbuf);
    t_in<<<1536, 256, 0, stream>>>(feats, bufA);

    unsigned short* cur = bufA;
    unsigned short* nxt = bufB;
    for (int i = 0; i < 2; ++i) {
        for (int dir = 0; dir < 2; ++dir) {
            const int tb = dir * 3;   // col: tensors 0..2, row: tensors 3..5
            const unsigned short* Wk = wbuf + (size_t)(tb + 0) * 131072 + (size_t)i * 65536;
            const unsigned short* Wq = wbuf + (size_t)(tb + 1) * 131072 + (size_t)i * 65536;
            const unsigned short* Wv = wbuf + (size_t)(tb + 2) * 131072 + (size_t)i * 65536;
            const float* bk = (const float*)d_in[4 + 2 * (tb + 0)] + i * 256;
            const float* bq = (const float*)d_in[4 + 2 * (tb + 1)] + i * 256;
            const float* bv = (const float*)d_in[4 + 2 * (tb + 2)] + i * 256;
            const int* lim_s = (dir == 0) ? num_rows : num_cols;
            const int* lim_m = (dir == 0) ? num_cols : num_rows;
            sa3<<<6144, 384, 40960, stream>>>(cur, nxt, Wk, Wq, Wv, bk, bq, bv, lim_s, lim_m);
            unsigned short* t = cur; cur = nxt; nxt = t;   // result now in `cur`
        }
    }

    // after 4 stages result is in bufA, layout [b][r][q][c]
    final_k<<<1536, 256, 0, stream>>>(cur, (float*)d_out);
    masks_kernel<<<576, 256, 0, stream>>>(num_rows, num_cols, (float*)d_out + 37748736);
}